// Round 11
// baseline (36.756 us; speedup 1.0000x reference)
//
#include <hip/hip_runtime.h>

// HighOrderActivationB, round 10: pair-lane tasks for dense stores + BC=256.
// r7: LDS gathers fixed TA saturation (67->36us). r9: occupancy null.
// r10 theory: residual = per-instruction store sparsity (16B/32B coverage
// -> 2x line transactions) + 28MB staging fetch.
// Two lanes share one task: each computes the sort (dup VALU, cheap), but
// gathers/stores only its 4-float half -> every store instr is a dense
// contiguous 512B run per 32 lanes. BC=256 halves staging fetch.

#define B_BATCH 4096
#define N_GROUPS 1024
#define N_TERMS 27
#define OUT_DIM 8
#define GC 16           // groups per block
#define BC 256          // batch rows per block
#define ROW_STRIDE 220  // dwords: 16B-aligned rows, 8 distinct bank starts

typedef float floatx4 __attribute__((ext_vector_type(4)));

__global__ __launch_bounds__(256)
void hoa_kernel(const float* __restrict__ X,
                const float* __restrict__ P,
                float* __restrict__ out) {
    __shared__ float lds[GC * ROW_STRIDE];   // 14080 B

    const int tid = threadIdx.x;
    const int g0 = blockIdx.x * GC;
    const int b0 = blockIdx.y * BC;

    // ---- stage params for GC groups: 16 rows x 54 float4 ----
    {
        const floatx4* P4 = (const floatx4*)(P + (size_t)g0 * (N_TERMS * OUT_DIM));
        floatx4* L4 = (floatx4*)lds;
        for (int i = tid; i < GC * 54; i += 256) {
            const int r = i / 54;
            const int c = i - r * 54;
            L4[r * (ROW_STRIDE / 4) + c] = P4[i];
        }
    }
    __syncthreads();

    const int half    = tid & 1;             // which float4 of the 8 outputs
    const int g_local = (tid & 31) >> 1;     // 0..15
    const int b_slot  = tid >> 5;            // 0..7
    const float* lg = lds + g_local * ROW_STRIDE + half * 4;
    const int g = g0 + g_local;

    #pragma unroll 4
    for (int it = 0; it < BC / 8; ++it) {    // 32 iterations
        const int b = b0 + b_slot + it * 8;

        // X read: pair lanes duplicate the same 12B (coalescer dedups);
        // per instr: 2 b-rows x 192B dense segments.
        const float* xp = X + (size_t)b * (N_GROUPS * 3) + g * 3;
        const float A0 = xp[0];
        const float A1 = xp[1];
        const float A2 = xp[2];

        float m0 = fabsf(A0), m1 = fabsf(A1), m2 = fabsf(A2);
        int t0 = (A0 >= 0.0f) ? 1 : -1;
        int t1 = (A1 >= 0.0f) ? 3 : -3;
        int t2 = (A2 >= 0.0f) ? 9 : -9;

        // stable ascending 3-sort by magnitude (strict > = stable)
        if (m0 > m1) { float tm=m0; m0=m1; m1=tm; int tt=t0; t0=t1; t1=tt; }
        if (m1 > m2) { float tm=m1; m1=m2; m2=tm; int tt=t1; t1=t2; t2=tt; }
        if (m0 > m1) { float tm=m0; m0=m1; m1=tm; int tt=t0; t0=t1; t1=tt; }

        const float c0 = m0;
        const float c1 = m1 - m0;
        const float c2 = m2 - m1;

        const int i2 = 13 + t2;
        const int i1 = i2 + t1;
        const int i0 = i1 + t0;

        // LDS gathers: this lane's half only -> 3x ds_read_b128
        const floatx4 g0h = *(const floatx4*)(lg + i0 * OUT_DIM);
        const floatx4 g1h = *(const floatx4*)(lg + i1 * OUT_DIM);
        const floatx4 g2h = *(const floatx4*)(lg + i2 * OUT_DIM);

        const floatx4 o = c0 * g0h + c1 * g1h + c2 * g2h;

        // dense store: lanes 0..31 cover contiguous 512B ascending (1 b-row),
        // lanes 32..63 another row -> fully dense per instruction.
        floatx4* op = (floatx4*)(out + (size_t)b * (N_GROUPS * OUT_DIM)
                                     + g * OUT_DIM + half * 4);
        *op = o;
    }
}

extern "C" void kernel_launch(void* const* d_in, const int* in_sizes, int n_in,
                              void* d_out, int out_size, void* d_ws, size_t ws_size,
                              hipStream_t stream) {
    const float* X = (const float*)d_in[0];
    const float* P = (const float*)d_in[1];
    float* out = (float*)d_out;

    dim3 grid(N_GROUPS / GC, B_BATCH / BC);   // (64, 16) = 1024 blocks = 4/CU
    hoa_kernel<<<grid, 256, 0, stream>>>(X, P, out);
}